// Round 11
// baseline (18539.195 us; speedup 1.0000x reference)
//
#include <hip/hip_runtime.h>
#include <hip/hip_fp16.h>
#include <math.h>

// Problem dims (fixed)
#define T_SEQ 4096
#define DIN   64
#define DM    1024
#define G4    4096              // 4*DM gate rows
#define LSTRIDE_W ((size_t)G4 * DM)   // per-layer Wih/Whh stride
#define LSTRIDE_B ((size_t)G4)        // per-layer bias stride

typedef unsigned long long u64;
typedef unsigned int u32;

__device__ __forceinline__ float sigmoidf_(float x) {
    return 1.0f / (1.0f + __expf(-x));
}
__device__ __forceinline__ float tanhf_(float x) {
    float ax = fabsf(x);
    float e  = __expf(-2.0f * ax);
    float t  = (1.0f - e) / (1.0f + e);
    return copysignf(t, x);
}
__device__ __forceinline__ float lrelu_(float x) {
    return x > 0.0f ? x : 0.01f * x;
}
__device__ __forceinline__ float f32_(u64 v) { return __uint_as_float((u32)v); }

// pack two fp32 -> one u32 of two f16 (v_cvt_pkrtz_f16_f32)
__device__ __forceinline__ u32 pk2_(float x, float y) {
    typedef __fp16 hv2 __attribute__((ext_vector_type(2)));
    union { hv2 h; u32 u; } c;
    c.h = __builtin_amdgcn_cvt_pkrtz(x, y);
    return c.u;
}
// fused f16-pair dot-accumulate
#if __has_builtin(__builtin_amdgcn_fdot2)
__device__ __forceinline__ float d2a_(u32 a, u32 b, float acc) {
    typedef __fp16 hv2 __attribute__((ext_vector_type(2)));
    union { u32 u; hv2 h; } ua, ub;
    ua.u = a; ub.u = b;
    return __builtin_amdgcn_fdot2(ua.h, ub.h, acc, false);
}
#else
__device__ __forceinline__ float d2a_(u32 a, u32 b, float acc) {
    union { u32 u; __half2 h; } ua, ub;
    ua.u = a; ub.u = b;
    float2 fa = __half22float2(ua.h);
    float2 fb = __half22float2(ub.h);
    return acc + fa.x * fb.x + fa.y * fb.y;
}
#endif

// ---------------------------------------------------------------------------
// K1: x[t,d] = leaky_relu(inp @ W1^T + b1)
// ---------------------------------------------------------------------------
__global__ __launch_bounds__(256) void k_input(const float* __restrict__ inp,
                                               const float* __restrict__ W1,
                                               const float* __restrict__ b1,
                                               float* __restrict__ x) {
    __shared__ float s_in[DIN];
    const int t   = blockIdx.x;
    const int tid = threadIdx.x;
    if (tid < DIN) s_in[tid] = inp[(size_t)t * DIN + tid];
    __syncthreads();
#pragma unroll
    for (int q = 0; q < 4; q++) {
        const int d = tid + q * 256;
        const float4* wr = (const float4*)(W1 + (size_t)d * DIN);
        float acc = 0.0f;
#pragma unroll
        for (int e = 0; e < 16; e++) {
            float4 w = wr[e];
            acc += w.x * s_in[e * 4 + 0] + w.y * s_in[e * 4 + 1] +
                   w.z * s_in[e * 4 + 2] + w.w * s_in[e * 4 + 3];
        }
        acc += b1[d];
        x[(size_t)t * DM + d] = lrelu_(acc);
    }
}

// ---------------------------------------------------------------------------
// K2: xg = x @ Wih0^T + (bih0+bhh0).  128x128 tile, BK=16.
// ---------------------------------------------------------------------------
__global__ __launch_bounds__(256) void k_gemm(const float* __restrict__ A,
                                              const float* __restrict__ B,
                                              const float* __restrict__ bih,
                                              const float* __restrict__ bhh,
                                              float* __restrict__ C) {
    const int K = DM;
    __shared__ float As[16][132];
    __shared__ float Bs[16][132];
    const int tid = threadIdx.x;
    const int m0 = blockIdx.y * 128, n0 = blockIdx.x * 128;
    const int tx = tid & 15, ty = tid >> 4;
    const int lr = tid >> 1;
    const int lc = (tid & 1) * 8;

    float acc[8][8] = {};
    const float4* ag = (const float4*)(A + (size_t)(m0 + lr) * K + lc);
    const float4* bg = (const float4*)(B + (size_t)(n0 + lr) * K + lc);

    for (int k0 = 0; k0 < K; k0 += 16) {
        float4 a0 = ag[0], a1 = ag[1];
        float4 b0 = bg[0], b1v = bg[1];
        ag += 4; bg += 4;
        __syncthreads();
        As[lc + 0][lr] = a0.x; As[lc + 1][lr] = a0.y; As[lc + 2][lr] = a0.z; As[lc + 3][lr] = a0.w;
        As[lc + 4][lr] = a1.x; As[lc + 5][lr] = a1.y; As[lc + 6][lr] = a1.z; As[lc + 7][lr] = a1.w;
        Bs[lc + 0][lr] = b0.x; Bs[lc + 1][lr] = b0.y; Bs[lc + 2][lr] = b0.z; Bs[lc + 3][lr] = b0.w;
        Bs[lc + 4][lr] = b1v.x; Bs[lc + 5][lr] = b1v.y; Bs[lc + 6][lr] = b1v.z; Bs[lc + 7][lr] = b1v.w;
        __syncthreads();
#pragma unroll
        for (int k = 0; k < 16; k++) {
            float a[8], b[8];
            *(float4*)&a[0] = *(const float4*)&As[k][ty * 8 + 0];
            *(float4*)&a[4] = *(const float4*)&As[k][ty * 8 + 4];
            *(float4*)&b[0] = *(const float4*)&Bs[k][tx * 8 + 0];
            *(float4*)&b[4] = *(const float4*)&Bs[k][tx * 8 + 4];
#pragma unroll
            for (int i = 0; i < 8; i++)
#pragma unroll
                for (int j = 0; j < 8; j++)
                    acc[i][j] += a[i] * b[j];
        }
    }
    float bj[8];
#pragma unroll
    for (int j = 0; j < 8; j++) {
        int n = n0 + tx * 8 + j;
        bj[j] = bih[n] + bhh[n];
    }
#pragma unroll
    for (int i = 0; i < 8; i++) {
        float4 v0, v1;
        v0.x = acc[i][0] + bj[0]; v0.y = acc[i][1] + bj[1];
        v0.z = acc[i][2] + bj[2]; v0.w = acc[i][3] + bj[3];
        v1.x = acc[i][4] + bj[4]; v1.y = acc[i][5] + bj[5];
        v1.z = acc[i][6] + bj[6]; v1.w = acc[i][7] + bj[7];
        float* cp = C + (size_t)(m0 + ty * 8 + i) * G4 + n0 + tx * 8;
        *(float4*)(cp + 0) = v0;
        *(float4*)(cp + 4) = v1;
    }
}

// ---------------------------------------------------------------------------
// K3: fused 2-layer scan, WAVE-SPECIALIZED (R11). 256 WGs x 4 waves, 1 WG/CU.
// ZERO per-round barriers. Waves are autonomous actors:
//   wave0: critical h0 chain. Gathers ALL 1024 sl0 slots itself (16 coalesced
//          u64 atomic loads/lane), dots 16 Whh0 rows (k split over 64 lanes,
//          pair mapping: lane l holds slots {2l+128j, 2l+128j+1}, j=0..7),
//          6-level butterfly, lanes 0-3 gate + publish tag t+1. Stages
//          gathered h0[t-1] to LDS mailbox for waves 2-3.
//   wave1: layer-1 combiner. Gathers sl1 (tag t = h1[t-2], 1 round of slack),
//          dots 16 Whh1 rows, merges Wih1 partials from gpB, gates,
//          publishes h1[t-1] tag t+1. Writes final output.
//   waves 2-3: Wih1 * h0[t-1] partials (8 rows each) from the h0 mailbox.
// Intra-WG sync: LDS seq counters (acquire/release, workgroup scope):
//   seqA  (wave0: h0 mailbox round t staged)        -> waves 2-3 wait >= t+1
//   seqC2/3 (waves 2-3: gpB round t written)        -> wave1 waits >= t+1,
//                                                      wave0 guard >= t-1
//   seqD  (wave1: gpB round t consumed)             -> waves 2-3 guard >= t-1
// DAG per round: wave0(t) -> w23(t) -> wave1(t); back-edges to t-1/t-2 only
// -> acyclic -> deadlock-free. Parity dbuf overwrite (t vs t+2) guarded by
// the consumption counters + the global all-to-all tag dependency (same
// 2-round-separation argument as R5).
// Global protocol unchanged: tagged u64 slots, parity dbuf, relaxed agent
// atomics, demand polls only (R9 lesson: no speculation).
// ---------------------------------------------------------------------------
__global__ __launch_bounds__(256, 1) void k_scan2(
        const float* __restrict__ xg,     // T x 4096 layer-0 preacts
        const float* __restrict__ Wih1,
        const float* __restrict__ Whh0,
        const float* __restrict__ Whh1,
        const float* __restrict__ bih1,
        const float* __restrict__ bhh1,
        u64* sl0,                         // [2][1024] tagged h0 slots
        u64* sl1,                         // [2][1024] tagged h1 slots
        float* __restrict__ out) {
    const int tid = threadIdx.x;
    const int w   = blockIdx.x;
    const int wv  = tid >> 6;             // wave 0..3
    const int ln  = tid & 63;             // lane

    // weights f16-pairs: [mat][ridx][j2][lane], ridx = g*4+s
    __shared__ uint4 wlds[3][16][2][64];  // 96 KB: 0=Whh0, 1=Whh1, 2=Wih1
    __shared__ uint4 h0st[2][2][64];      // 4 KB h0 mailbox (parity dbuf)
    __shared__ float gpB[2][16];          // Wih1*h0 partials (parity dbuf)
    __shared__ int seqA, seqC2, seqC3, seqD;

    if (tid == 0) { seqA = 0; seqC2 = 0; seqC3 = 0; seqD = 0; }

    // ---- weight prologue: each wave self-stores its own slice ----
    {
        const float* mat; int mi, rA, rB;
        if (wv == 0)      { mat = Whh0; mi = 0; rA = 0; rB = 16; }
        else if (wv == 1) { mat = Whh1; mi = 1; rA = 0; rB = 16; }
        else if (wv == 2) { mat = Wih1; mi = 2; rA = 0; rB = 8;  }
        else              { mat = Wih1; mi = 2; rA = 8; rB = 16; }
        for (int ridx = rA; ridx < rB; ridx++) {
            const int g = ridx >> 2, s = ridx & 3;
            const float* rp = mat + (size_t)(g * DM + w * 4 + s) * DM;
#pragma unroll
            for (int j2 = 0; j2 < 2; j2++) {
                uint4 q;
                const float* e0 = rp + 2 * ln + 128 * (j2 * 4 + 0);
                const float* e1 = rp + 2 * ln + 128 * (j2 * 4 + 1);
                const float* e2 = rp + 2 * ln + 128 * (j2 * 4 + 2);
                const float* e3 = rp + 2 * ln + 128 * (j2 * 4 + 3);
                q.x = pk2_(e0[0], e0[1]);
                q.y = pk2_(e1[0], e1[1]);
                q.z = pk2_(e2[0], e2[1]);
                q.w = pk2_(e3[0], e3[1]);
                wlds[mi][ridx][j2][ln] = q;
            }
        }
    }
    __syncthreads();   // the ONLY barrier

    if (wv == 0) {
        // ================== wave 0: critical h0 chain ==================
        float c0 = 0.f, h0v = 0.f;
        float xgr0 = 0.f, xgr1 = 0.f, xgr2 = 0.f, xgr3 = 0.f;
        if (ln < 4) {
            xgr0 = xg[0 * DM + w * 4 + ln];
            xgr1 = xg[1 * DM + w * 4 + ln];
            xgr2 = xg[2 * DM + w * 4 + ln];
            xgr3 = xg[3 * DM + w * 4 + ln];
        }
        uint4 hp0 = {0, 0, 0, 0}, hp1 = {0, 0, 0, 0};

        for (int t = 0; t <= T_SEQ; t++) {
            const int par = t & 1;
            if (t > 0) {
                const u64* base = sl0 + (size_t)par * 1024;
                const u32 want = (u32)t;
                u64 v[16];
                for (;;) {
#pragma unroll
                    for (int j = 0; j < 8; j++) {
                        v[2 * j]     = __hip_atomic_load(base + 2 * ln + 128 * j,
                                          __ATOMIC_RELAXED, __HIP_MEMORY_SCOPE_AGENT);
                        v[2 * j + 1] = __hip_atomic_load(base + 2 * ln + 128 * j + 1,
                                          __ATOMIC_RELAXED, __HIP_MEMORY_SCOPE_AGENT);
                    }
                    int ok = 1;
#pragma unroll
                    for (int k = 0; k < 16; k++) ok &= ((u32)(v[k] >> 32) == want);
                    if (__all(ok)) break;
                }
                hp0.x = pk2_(f32_(v[0]),  f32_(v[1]));
                hp0.y = pk2_(f32_(v[2]),  f32_(v[3]));
                hp0.z = pk2_(f32_(v[4]),  f32_(v[5]));
                hp0.w = pk2_(f32_(v[6]),  f32_(v[7]));
                hp1.x = pk2_(f32_(v[8]),  f32_(v[9]));
                hp1.y = pk2_(f32_(v[10]), f32_(v[11]));
                hp1.z = pk2_(f32_(v[12]), f32_(v[13]));
                hp1.w = pk2_(f32_(v[14]), f32_(v[15]));
            }
            // dot 16 Whh0 rows
            float acc[16];
#pragma unroll
            for (int ridx = 0; ridx < 16; ridx++) {
                uint4 qa = wlds[0][ridx][0][ln];
                uint4 qb = wlds[0][ridx][1][ln];
                float a = 0.f;
                a = d2a_(qa.x, hp0.x, a); a = d2a_(qa.y, hp0.y, a);
                a = d2a_(qa.z, hp0.z, a); a = d2a_(qa.w, hp0.w, a);
                a = d2a_(qb.x, hp1.x, a); a = d2a_(qb.y, hp1.y, a);
                a = d2a_(qb.z, hp1.z, a); a = d2a_(qb.w, hp1.w, a);
                acc[ridx] = a;
            }
#pragma unroll
            for (int m = 1; m <= 32; m <<= 1) {
#pragma unroll
                for (int ridx = 0; ridx < 16; ridx++)
                    acc[ridx] += __shfl_xor(acc[ridx], m, 64);
            }
            if (ln < 4 && t < T_SEQ) {
                float pi = acc[ln]      + xgr0;
                float pf = acc[4 + ln]  + xgr1;
                float pg = acc[8 + ln]  + xgr2;
                float po = acc[12 + ln] + xgr3;
                c0 = sigmoidf_(pf) * c0 + sigmoidf_(pi) * tanhf_(pg);
                h0v = sigmoidf_(po) * tanhf_(c0);
                u64 vv = ((u64)(u32)(t + 1) << 32) | (u64)__float_as_uint(h0v);
                __hip_atomic_store(sl0 + (size_t)((t + 1) & 1) * 1024 + w * 4 + ln,
                                   vv, __ATOMIC_RELAXED, __HIP_MEMORY_SCOPE_AGENT);
            }
            // xg prefetch for t+1 (off-chain)
            if (ln < 4 && t + 1 < T_SEQ) {
                const float* xp = xg + (size_t)(t + 1) * G4 + w * 4 + ln;
                xgr0 = xp[0]; xgr1 = xp[DM]; xgr2 = xp[2 * DM]; xgr3 = xp[3 * DM];
            }
            // stage gathered h0[t-1] for waves 2-3 (guarded parity overwrite)
            while (__hip_atomic_load(&seqC2, __ATOMIC_ACQUIRE, __HIP_MEMORY_SCOPE_WORKGROUP) < t - 1 ||
                   __hip_atomic_load(&seqC3, __ATOMIC_ACQUIRE, __HIP_MEMORY_SCOPE_WORKGROUP) < t - 1) {}
            h0st[par][0][ln] = hp0;
            h0st[par][1][ln] = hp1;
            if (ln == 0)
                __hip_atomic_store(&seqA, t + 1, __ATOMIC_RELEASE, __HIP_MEMORY_SCOPE_WORKGROUP);
        }
    } else if (wv == 1) {
        // ================== wave 1: layer-1 combiner ==================
        float c1 = 0.f, h1v = 0.f;
        float b1s0 = 0.f, b1s1 = 0.f, b1s2 = 0.f, b1s3 = 0.f;
        if (ln < 4) {
            b1s0 = bih1[0 * DM + w * 4 + ln] + bhh1[0 * DM + w * 4 + ln];
            b1s1 = bih1[1 * DM + w * 4 + ln] + bhh1[1 * DM + w * 4 + ln];
            b1s2 = bih1[2 * DM + w * 4 + ln] + bhh1[2 * DM + w * 4 + ln];
            b1s3 = bih1[3 * DM + w * 4 + ln] + bhh1[3 * DM + w * 4 + ln];
        }
        uint4 hq0 = {0, 0, 0, 0}, hq1 = {0, 0, 0, 0};

        for (int t = 0; t <= T_SEQ; t++) {
            const int par = t & 1;
            if (t > 0) {
                const u64* base = sl1 + (size_t)par * 1024;
                const u32 want = (u32)t;
                u64 v[16];
                for (;;) {
#pragma unroll
                    for (int j = 0; j < 8; j++) {
                        v[2 * j]     = __hip_atomic_load(base + 2 * ln + 128 * j,
                                          __ATOMIC_RELAXED, __HIP_MEMORY_SCOPE_AGENT);
                        v[2 * j + 1] = __hip_atomic_load(base + 2 * ln + 128 * j + 1,
                                          __ATOMIC_RELAXED, __HIP_MEMORY_SCOPE_AGENT);
                    }
                    int ok = 1;
#pragma unroll
                    for (int k = 0; k < 16; k++) ok &= ((u32)(v[k] >> 32) == want);
                    if (__all(ok)) break;
                }
                hq0.x = pk2_(f32_(v[0]),  f32_(v[1]));
                hq0.y = pk2_(f32_(v[2]),  f32_(v[3]));
                hq0.z = pk2_(f32_(v[4]),  f32_(v[5]));
                hq0.w = pk2_(f32_(v[6]),  f32_(v[7]));
                hq1.x = pk2_(f32_(v[8]),  f32_(v[9]));
                hq1.y = pk2_(f32_(v[10]), f32_(v[11]));
                hq1.z = pk2_(f32_(v[12]), f32_(v[13]));
                hq1.w = pk2_(f32_(v[14]), f32_(v[15]));
            }
            // dot 16 Whh1 rows with h1[t-2]
            float acc[16];
#pragma unroll
            for (int ridx = 0; ridx < 16; ridx++) {
                uint4 qa = wlds[1][ridx][0][ln];
                uint4 qb = wlds[1][ridx][1][ln];
                float a = 0.f;
                a = d2a_(qa.x, hq0.x, a); a = d2a_(qa.y, hq0.y, a);
                a = d2a_(qa.z, hq0.z, a); a = d2a_(qa.w, hq0.w, a);
                a = d2a_(qb.x, hq1.x, a); a = d2a_(qb.y, hq1.y, a);
                a = d2a_(qb.z, hq1.z, a); a = d2a_(qb.w, hq1.w, a);
                acc[ridx] = a;
            }
#pragma unroll
            for (int m = 1; m <= 32; m <<= 1) {
#pragma unroll
                for (int ridx = 0; ridx < 16; ridx++)
                    acc[ridx] += __shfl_xor(acc[ridx], m, 64);
            }
            // merge Wih1*h0 partials
            while (__hip_atomic_load(&seqC2, __ATOMIC_ACQUIRE, __HIP_MEMORY_SCOPE_WORKGROUP) < t + 1 ||
                   __hip_atomic_load(&seqC3, __ATOMIC_ACQUIRE, __HIP_MEMORY_SCOPE_WORKGROUP) < t + 1) {}
            float pi = 0.f, pf = 0.f, pg = 0.f, po = 0.f;
            if (ln < 4) {
                pi = acc[ln]      + gpB[par][ln]      + b1s0;
                pf = acc[4 + ln]  + gpB[par][4 + ln]  + b1s1;
                pg = acc[8 + ln]  + gpB[par][8 + ln]  + b1s2;
                po = acc[12 + ln] + gpB[par][12 + ln] + b1s3;
            }
            if (ln == 0)
                __hip_atomic_store(&seqD, t + 1, __ATOMIC_RELEASE, __HIP_MEMORY_SCOPE_WORKGROUP);
            if (ln < 4) {
                if (t > 0) {
                    c1 = sigmoidf_(pf) * c1 + sigmoidf_(pi) * tanhf_(pg);
                    h1v = sigmoidf_(po) * tanhf_(c1);
                }
                if (t < T_SEQ) {
                    u64 vv = ((u64)(u32)(t + 1) << 32) | (u64)__float_as_uint(h1v);
                    __hip_atomic_store(sl1 + (size_t)((t + 1) & 1) * 1024 + w * 4 + ln,
                                       vv, __ATOMIC_RELAXED, __HIP_MEMORY_SCOPE_AGENT);
                }
            }
        }
        if (ln < 4) out[w * 4 + ln] = lrelu_(h1v);   // h1[T-1]
    } else {
        // ============== waves 2-3: Wih1 * h0[t-1] partials ==============
        const int rbase = (wv == 2) ? 0 : 8;
        int* seqC = (wv == 2) ? &seqC2 : &seqC3;
        for (int t = 0; t <= T_SEQ; t++) {
            const int par = t & 1;
            // gpB overwrite guard: wave1 consumed round t-2
            while (__hip_atomic_load(&seqD, __ATOMIC_ACQUIRE, __HIP_MEMORY_SCOPE_WORKGROUP) < t - 1) {}
            // h0 mailbox for round t
            while (__hip_atomic_load(&seqA, __ATOMIC_ACQUIRE, __HIP_MEMORY_SCOPE_WORKGROUP) < t + 1) {}
            uint4 ha0 = h0st[par][0][ln];
            uint4 ha1 = h0st[par][1][ln];
            float acc[8];
#pragma unroll
            for (int i = 0; i < 8; i++) {
                uint4 qa = wlds[2][rbase + i][0][ln];
                uint4 qb = wlds[2][rbase + i][1][ln];
                float a = 0.f;
                a = d2a_(qa.x, ha0.x, a); a = d2a_(qa.y, ha0.y, a);
                a = d2a_(qa.z, ha0.z, a); a = d2a_(qa.w, ha0.w, a);
                a = d2a_(qb.x, ha1.x, a); a = d2a_(qb.y, ha1.y, a);
                a = d2a_(qb.z, ha1.z, a); a = d2a_(qb.w, ha1.w, a);
                acc[i] = a;
            }
#pragma unroll
            for (int m = 1; m <= 32; m <<= 1) {
#pragma unroll
                for (int i = 0; i < 8; i++)
                    acc[i] += __shfl_xor(acc[i], m, 64);
            }
            if (ln < 8) gpB[par][rbase + ln] = acc[ln];
            if (ln == 0)
                __hip_atomic_store(seqC, t + 1, __ATOMIC_RELEASE, __HIP_MEMORY_SCOPE_WORKGROUP);
        }
    }
}

// ---------------------------------------------------------------------------
extern "C" void kernel_launch(void* const* d_in, const int* in_sizes, int n_in,
                              void* d_out, int out_size, void* d_ws, size_t ws_size,
                              hipStream_t stream) {
    const float* inp = (const float*)d_in[0];   // 4096 x 64
    const float* W1  = (const float*)d_in[1];   // 1024 x 64
    const float* b1  = (const float*)d_in[2];   // 1024
    const float* Wih = (const float*)d_in[3];   // 2 x 4096 x 1024
    const float* Whh = (const float*)d_in[4];   // 2 x 4096 x 1024
    const float* bih = (const float*)d_in[5];   // 2 x 4096
    const float* bhh = (const float*)d_in[6];   // 2 x 4096
    float* out = (float*)d_out;                 // 1024

    // workspace layout
    float* x   = (float*)d_ws;                          // 4096*1024 f32
    float* xg  = x + (size_t)T_SEQ * DM;                // 4096*4096 f32
    u64*   sl0 = (u64*)(xg + (size_t)T_SEQ * G4);       // 2*1024 u64
    u64*   sl1 = sl0 + 2048;                            // 2*1024 u64
    (void)in_sizes; (void)n_in; (void)out_size; (void)ws_size;

    // Phase 1: input projection
    k_input<<<dim3(T_SEQ), dim3(256), 0, stream>>>(inp, W1, b1, x);

    // Phase 2: xg = x @ Wih0^T + (bih0+bhh0)
    k_gemm<<<dim3(32, 32), dim3(256), 0, stream>>>(x, Wih, bih, bhh, xg);

    // Phase 3: fused 2-layer scan, wave-specialized, zero per-round barriers
    k_scan2<<<dim3(256), dim3(256), 0, stream>>>(
        xg, Wih + LSTRIDE_W, Whh, Whh + LSTRIDE_W,
        bih + LSTRIDE_B, bhh + LSTRIDE_B, sl0, sl1, out);
}